// Round 25
// baseline (41.815 us; speedup 1.0000x reference)
//
#include <hip/hip_runtime.h>

#define HW 262144            // 512*512
#define TSIZE 524288         // 2^19 entries per level
#define HMASK 524287u
#define PRIME2 2654435761u

#define NLDS 11              // levels 0..10 staged in LDS (f16-packed entries)
#define ETOT 9069            // sum of (NS[l]+2)^2 for l<11 (entries)
#define EPAD 9072            // padded to uint4 multiple (36,288 B)
#define QTOT 45999           // 63^2+75^2+90^2+108^2+129^2 cells (levels 11..15)
#define QU4_OFF 2268         // EPAD u32 = 36,288 B -> /16 = 2268 uint4
#define WS_NEED (36288 + QTOT * 16)   // 772,272 B
#define BLK 512              // 1024 blocks = 4/CU exactly (36.3KB LDS), no tail
#define PPT 2                // pixels per thread (low VGPR -> 32 waves/CU)
#define SCALE 1024.0f        // lift f16 values out of subnormal range (exact pow2)
#define INV_SCALE 0.0009765625f  // 2^-10, exact

typedef float    f2v __attribute__((ext_vector_type(2)));
typedef _Float16 h2v __attribute__((ext_vector_type(2)));
typedef _Float16 h8v __attribute__((ext_vector_type(8)));

__device__ __constant__ int c_W11[11]   = {10, 11, 13, 15, 18, 22, 26, 31, 37, 44, 52};
__device__ __constant__ int c_EOFF[12]  = {0, 100, 221, 390, 615, 939, 1423, 2099,
                                           3060, 4429, 6365, 9069};
__device__ __constant__ int c_WQ[5]     = {63, 75, 90, 108, 129};
__device__ __constant__ int c_QOFF[6]   = {0, 3969, 9594, 17694, 29358, 45999};

// Reference semantics (locked R1-R7): JAX/XLA f32:
//   hx = int32(fl32(cx*n)); bx = floorf(fl32(cx*rcp)), rcp = fl32(1/fl32(1/n));
//   NS[15] = 127.
// Ladder: R7 93 -> R11 47.9 -> R19 42.8 -> R21 41.0 -> R23 40.7 -> R24 40.85
// (null: VGPR cap wasn't binding; R23 already at 32 waves/CU = HW max).
// Occupancy maxed + plateau => wall is not latency capacity. Last un-falsified
// mechanism: per-CU PHASE CONVOY (11 LDS-pipe levels then 5 VALU-only quad
// levels; all waves in lockstep leave one pipe idle at a time).
// R25: single change vs R23 -- interleave quad blends INTO the LDS sequence
// (L0,L1,Q0,L2,L3,Q1,...): flat instruction mix, both pipes fed throughout.

__device__ __forceinline__ unsigned pack_h2(float a, float b) {
    h2v h; h[0] = (_Float16)(a * SCALE); h[1] = (_Float16)(b * SCALE);
    return __builtin_bit_cast(unsigned, h);
}

// ---- phase 1: build dense scratch: f16 entries (lvls 0-10) + f16 quads (11-15) ----
__global__ __launch_bounds__(256)
void dehash_kernel(const float* __restrict__ table, unsigned* __restrict__ wsu)
{
    const int e = blockIdx.x * 256 + threadIdx.x;
    const float2* __restrict__ tab2 = reinterpret_cast<const float2*>(table);

    if (e < ETOT) {
        int l = 0;
        #pragma unroll
        for (int i = 1; i < NLDS; ++i) l += (e >= c_EOFF[i]);
        const int W   = c_W11[l];
        const int rel = e - c_EOFF[l];
        const int j   = rel / W;
        const int i2  = rel - j * W;
        const unsigned idx = ((unsigned)i2 ^ ((unsigned)j * PRIME2)) & HMASK;
        const float2 v = tab2[(size_t)l * TSIZE + idx];
        wsu[e] = pack_h2(v.x, v.y);
    } else if (e < ETOT + QTOT) {
        const int eq = e - ETOT;
        int k = 0;
        #pragma unroll
        for (int i = 1; i < 5; ++i) k += (eq >= c_QOFF[i]);
        const int W   = c_WQ[k];
        const int rel = eq - c_QOFF[k];
        const int j   = rel / W;
        const int i2  = rel - j * W;
        const float2* __restrict__ tabl = tab2 + (size_t)(11 + k) * TSIZE;
        const unsigned jp0 = (unsigned)j * PRIME2;
        const unsigned jp1 = (unsigned)(j + 1) * PRIME2;
        const float2 f00 = tabl[((unsigned)i2       ^ jp0) & HMASK];
        const float2 f10 = tabl[((unsigned)(i2 + 1) ^ jp0) & HMASK];
        const float2 f01 = tabl[((unsigned)i2       ^ jp1) & HMASK];
        const float2 f11 = tabl[((unsigned)(i2 + 1) ^ jp1) & HMASK];
        uint4 q;
        q.x = pack_h2(f00.x, f00.y);
        q.y = pack_h2(f10.x, f10.y);
        q.z = pack_h2(f01.x, f01.y);
        q.w = pack_h2(f11.x, f11.y);
        reinterpret_cast<uint4*>(wsu)[QU4_OFF + eq] = q;
    }
}

__device__ __forceinline__ float2 dec_h2(unsigned u) {
    const h2v h = __builtin_bit_cast(h2v, u);
    return make_float2((float)h[0], (float)h[1]);
}

// ---- phase 2: fused encode, interleaved LDS/quad level schedule ----
__global__ __launch_bounds__(BLK, 8)
void hashenc_fused(const float* __restrict__ coord,
                   const unsigned* __restrict__ wsu,
                   float* __restrict__ out)
{
    constexpr int NS[11]   = {8, 9, 11, 13, 16, 20, 24, 29, 35, 42, 50};
    constexpr int W11[11]  = {10, 11, 13, 15, 18, 22, 26, 31, 37, 44, 52};
    constexpr int EOFF[11] = {0, 100, 221, 390, 615, 939, 1423, 2099, 3060, 4429,
                              6365};
    constexpr int NSD[5]   = {61, 73, 88, 106, 127};
    constexpr int WQ[5]    = {63, 75, 90, 108, 129};
    constexpr int QOFF[5]  = {0, 3969, 9594, 17694, 29358};

    __shared__ __align__(16) unsigned smem[EPAD];   // 36,288 B -> 4 blocks/CU

    // ---- stage f16 entries from dense scratch (coalesced uint4) ----
    {
        const uint4* __restrict__ src = reinterpret_cast<const uint4*>(wsu);
        uint4* __restrict__ dst = reinterpret_cast<uint4*>(smem);
        for (int e = threadIdx.x; e < EPAD / 4; e += BLK)
            dst[e] = src[e];
    }

    const int g   = blockIdx.x * BLK + threadIdx.x;   // 0..524287
    const int P   = g << 1;                           // first of 2 pixels
    const int b   = P >> 18;                          // batch (HW = 2^18)
    const int pos = P & (HW - 1);

    const float* cbase = coord + (size_t)b * (2 * HW);
    const float2 cxp = *reinterpret_cast<const float2*>(cbase + pos);
    const float2 cyp = *reinterpret_cast<const float2*>(cbase + HW + pos);
    const float cxa[PPT] = {cxp.x, cxp.y};
    const float cya[PPT] = {cyp.x, cyp.y};

    float* outb = out + (size_t)b * (32 * HW) + pos;

    __syncthreads();

    // ---- issue all 10 direct quad loads NOW ----
    uint4 q[5][PPT];
    {
        const uint4* __restrict__ quad = reinterpret_cast<const uint4*>(wsu) + QU4_OFF;
        #pragma unroll
        for (int k = 0; k < 5; ++k) {
            const float n = (float)NSD[k];
            #pragma unroll
            for (int p = 0; p < PPT; ++p) {
                const int hx = (int)(cxa[p] * n);
                const int hy = (int)(cya[p] * n);
                q[k][p] = quad[QOFF[k] + hy * WQ[k] + hx];
            }
        }
    }

    // ---- interleaved schedule: L0,L1,Q0,L2,L3,Q1,L4,L5,Q2,L6,L7,Q3,L8,L9,Q4,L10
    //      (quad blends are VALU-only filler between ds_read-bound LDS levels)
    #pragma unroll
    for (int step = 0; step < 16; ++step) {
        // mapping: steps {2,5,8,11,14} -> quad k = step/3; others -> LDS level
        const bool is_quad = (step % 3 == 2) && (step / 3 < 5);
        if (is_quad) {
            const int   k   = step / 3;
            const int   l   = 11 + k;
            const float n   = (float)NSD[k];
            const float inv = 1.0f / n;
            const float rcp = 1.0f / inv;

            float o0[PPT], o1[PPT];
            #pragma unroll
            for (int p = 0; p < PPT; ++p) {
                const float cx = cxa[p], cy = cya[p];
                const float bx = floorf(cx * rcp);
                const float by = floorf(cy * rcp);
                const h8v h = __builtin_bit_cast(h8v, q[k][p]);
                const float wx_lo = ((bx + 1.0f) * inv - cx) * n;
                const float wx_hi = (cx - bx * inv) * n;
                const float wy_lo = ((by + 1.0f) * inv - cy) * n;
                const float wy_hi = (cy - by * inv) * n;
                const float r1x = (float)h[0] * wx_lo + (float)h[2] * wx_hi;
                const float r1y = (float)h[1] * wx_lo + (float)h[3] * wx_hi;
                const float r2x = (float)h[4] * wx_lo + (float)h[6] * wx_hi;
                const float r2y = (float)h[5] * wx_lo + (float)h[7] * wx_hi;
                o0[p] = (r1x * wy_lo + r2x * wy_hi) * INV_SCALE;
                o1[p] = (r1y * wy_lo + r2y * wy_hi) * INV_SCALE;
            }
            __builtin_nontemporal_store(f2v{o0[0], o0[1]},
                                        (f2v*)(outb + (size_t)(2 * l)     * HW));
            __builtin_nontemporal_store(f2v{o1[0], o1[1]},
                                        (f2v*)(outb + (size_t)(2 * l + 1) * HW));
        } else {
            const int   l   = step - step / 3;   // 0,1,2,3,...,10
            const float n   = (float)NS[l];
            const float inv = 1.0f / n;
            const float rcp = 1.0f / inv;
            const int   W   = W11[l];
            const unsigned* __restrict__ sl = smem + EOFF[l];

            float o0[PPT], o1[PPT];
            #pragma unroll
            for (int p = 0; p < PPT; ++p) {
                const float cx = cxa[p], cy = cya[p];
                const int hx = (int)(cx * n);
                const int hy = (int)(cy * n);
                const float bx = floorf(cx * rcp);
                const float by = floorf(cy * rcp);
                const int base = hy * W + hx;
                const float2 f00 = dec_h2(sl[base]);
                const float2 f10 = dec_h2(sl[base + 1]);
                const float2 f01 = dec_h2(sl[base + W]);
                const float2 f11 = dec_h2(sl[base + W + 1]);
                const float wx_lo = ((bx + 1.0f) * inv - cx) * n;
                const float wx_hi = (cx - bx * inv) * n;
                const float wy_lo = ((by + 1.0f) * inv - cy) * n;
                const float wy_hi = (cy - by * inv) * n;
                const float r1x = f00.x * wx_lo + f10.x * wx_hi;
                const float r1y = f00.y * wx_lo + f10.y * wx_hi;
                const float r2x = f01.x * wx_lo + f11.x * wx_hi;
                const float r2y = f01.y * wx_lo + f11.y * wx_hi;
                o0[p] = (r1x * wy_lo + r2x * wy_hi) * INV_SCALE;
                o1[p] = (r1y * wy_lo + r2y * wy_hi) * INV_SCALE;
            }
            __builtin_nontemporal_store(f2v{o0[0], o0[1]},
                                        (f2v*)(outb + (size_t)(2 * l)     * HW));
            __builtin_nontemporal_store(f2v{o1[0], o1[1]},
                                        (f2v*)(outb + (size_t)(2 * l + 1) * HW));
        }
    }
}

// ---- fallback (ws too small): R11 structure, proven 47.9us ----
__global__ __launch_bounds__(1024)
void hashenc_r11(const float* __restrict__ coord,
                 const float* __restrict__ table,
                 float* __restrict__ out)
{
    constexpr int NS[13]  = {8, 9, 11, 13, 16, 20, 24, 29, 35, 42, 50, 61, 73};
    constexpr int OFF[13] = {0, 100, 221, 390, 615, 939, 1423, 2099, 3060, 4429,
                             6365, 9069, 13038};
    constexpr int NSD[3]  = {88, 106, 127};

    extern __shared__ float2 smemd[];
    const float2* __restrict__ tab2 = reinterpret_cast<const float2*>(table);

    #pragma unroll
    for (int l = 0; l < 13; ++l) {
        const int W  = NS[l] + 2;
        const int SZ = W * W;
        const float2* __restrict__ tabl = tab2 + (size_t)l * TSIZE;
        for (int e = threadIdx.x; e < SZ; e += 1024) {
            const int j = e / W;
            const int i = e - j * W;
            smemd[OFF[l] + e] = tabl[((unsigned)i ^ ((unsigned)j * PRIME2)) & HMASK];
        }
    }

    const int g   = blockIdx.x * 1024 + threadIdx.x;
    const int P   = g << 1;
    const int b   = P >> 18;
    const int pos = P & (HW - 1);
    const float* cbase = coord + (size_t)b * (2 * HW);
    const float2 cxp = *reinterpret_cast<const float2*>(cbase + pos);
    const float2 cyp = *reinterpret_cast<const float2*>(cbase + HW + pos);
    const float cxa[2] = {cxp.x, cxp.y};
    const float cya[2] = {cyp.x, cyp.y};
    float* outb = out + (size_t)b * (32 * HW) + pos;

    __syncthreads();

    float2 gd[3][8];
    #pragma unroll
    for (int k = 0; k < 3; ++k) {
        const float n = (float)NSD[k];
        const float2* __restrict__ tabl = tab2 + (size_t)(13 + k) * TSIZE;
        #pragma unroll
        for (int p = 0; p < 2; ++p) {
            const int hx = (int)(cxa[p] * n);
            const int hy = (int)(cya[p] * n);
            const unsigned hyp0 = (unsigned)hy * PRIME2;
            const unsigned hyp1 = (unsigned)(hy + 1) * PRIME2;
            gd[k][p * 4 + 0] = tabl[((unsigned)hx       ^ hyp0) & HMASK];
            gd[k][p * 4 + 1] = tabl[((unsigned)(hx + 1) ^ hyp0) & HMASK];
            gd[k][p * 4 + 2] = tabl[((unsigned)hx       ^ hyp1) & HMASK];
            gd[k][p * 4 + 3] = tabl[((unsigned)(hx + 1) ^ hyp1) & HMASK];
        }
    }

    #pragma unroll
    for (int l = 0; l < 13; ++l) {
        const float n   = (float)NS[l];
        const float inv = 1.0f / n;
        const float rcp = 1.0f / inv;
        const int   W   = NS[l] + 2;
        const float2* __restrict__ sl = smemd + OFF[l];
        float o0[2], o1[2];
        #pragma unroll
        for (int p = 0; p < 2; ++p) {
            const float cx = cxa[p], cy = cya[p];
            const int hx = (int)(cx * n);
            const int hy = (int)(cy * n);
            const float bx = floorf(cx * rcp);
            const float by = floorf(cy * rcp);
            const int base = hy * W + hx;
            const float2 f00 = sl[base], f10 = sl[base + 1];
            const float2 f01 = sl[base + W], f11 = sl[base + W + 1];
            const float wx_lo = ((bx + 1.0f) * inv - cx) * n;
            const float wx_hi = (cx - bx * inv) * n;
            const float wy_lo = ((by + 1.0f) * inv - cy) * n;
            const float wy_hi = (cy - by * inv) * n;
            const float r1x = f00.x * wx_lo + f10.x * wx_hi;
            const float r1y = f00.y * wx_lo + f10.y * wx_hi;
            const float r2x = f01.x * wx_lo + f11.x * wx_hi;
            const float r2y = f01.y * wx_lo + f11.y * wx_hi;
            o0[p] = r1x * wy_lo + r2x * wy_hi;
            o1[p] = r1y * wy_lo + r2y * wy_hi;
        }
        *reinterpret_cast<float2*>(outb + (size_t)(2 * l)     * HW) = make_float2(o0[0], o0[1]);
        *reinterpret_cast<float2*>(outb + (size_t)(2 * l + 1) * HW) = make_float2(o1[0], o1[1]);
    }

    #pragma unroll
    for (int k = 0; k < 3; ++k) {
        const int   l   = 13 + k;
        const float n   = (float)NSD[k];
        const float inv = 1.0f / n;
        const float rcp = 1.0f / inv;
        float o0[2], o1[2];
        #pragma unroll
        for (int p = 0; p < 2; ++p) {
            const float cx = cxa[p], cy = cya[p];
            const float bx = floorf(cx * rcp);
            const float by = floorf(cy * rcp);
            const float2 f00 = gd[k][p * 4 + 0], f10 = gd[k][p * 4 + 1];
            const float2 f01 = gd[k][p * 4 + 2], f11 = gd[k][p * 4 + 3];
            const float wx_lo = ((bx + 1.0f) * inv - cx) * n;
            const float wx_hi = (cx - bx * inv) * n;
            const float wy_lo = ((by + 1.0f) * inv - cy) * n;
            const float wy_hi = (cy - by * inv) * n;
            const float r1x = f00.x * wx_lo + f10.x * wx_hi;
            const float r1y = f00.y * wx_lo + f10.y * wx_hi;
            const float r2x = f01.x * wx_lo + f11.x * wx_hi;
            const float r2y = f01.y * wx_lo + f11.y * wx_hi;
            o0[p] = r1x * wy_lo + r2x * wy_hi;
            o1[p] = r1y * wy_lo + r2y * wy_hi;
        }
        *reinterpret_cast<float2*>(outb + (size_t)(2 * l)     * HW) = make_float2(o0[0], o0[1]);
        *reinterpret_cast<float2*>(outb + (size_t)(2 * l + 1) * HW) = make_float2(o1[0], o1[1]);
    }
}

extern "C" void kernel_launch(void* const* d_in, const int* in_sizes, int n_in,
                              void* d_out, int out_size, void* d_ws, size_t ws_size,
                              hipStream_t stream) {
    const float* coord = (const float*)d_in[0];
    const float* table = (const float*)d_in[1];
    if (n_in >= 2 && in_sizes[0] > in_sizes[1]) {   // size-based disambiguation
        coord = (const float*)d_in[1];
        table = (const float*)d_in[0];
    }
    float* out = (float*)d_out;

    if (ws_size >= (size_t)WS_NEED && d_ws != nullptr) {
        unsigned* wsu = (unsigned*)d_ws;
        // phase 1: 9069 entries + 45999 quad cells = 55068 -> 216 blocks
        dehash_kernel<<<(ETOT + QTOT + 255) / 256, 256, 0, stream>>>(table, wsu);
        // phase 2: 1M px / (512 thr * 2 px) = 1024 blocks = 4/CU exactly (no tail)
        hashenc_fused<<<1024, BLK, 0, stream>>>(coord, wsu, out);
    } else {
        const int lds_bytes = 18663 * (int)sizeof(float2);
        (void)hipFuncSetAttribute((const void*)hashenc_r11,
                                  hipFuncAttributeMaxDynamicSharedMemorySize,
                                  lds_bytes);
        hashenc_r11<<<512, 1024, lds_bytes, stream>>>(coord, table, out);
    }
}

// Round 26
// 40.528 us; speedup vs baseline: 1.0317x; 1.0317x over previous
//
#include <hip/hip_runtime.h>

#define HW 262144            // 512*512
#define TSIZE 524288         // 2^19 entries per level
#define HMASK 524287u
#define PRIME2 2654435761u

#define NLDS 11              // levels 0..10 staged in LDS (f16-packed entries)
#define ETOT 9069            // sum of (NS[l]+2)^2 for l<11 (entries)
#define EPAD 9072            // padded to uint4 multiple (36,288 B)
#define QTOT 45999           // 63^2+75^2+90^2+108^2+129^2 cells (levels 11..15)
#define QU4_OFF 2268         // EPAD u32 = 36,288 B -> /16 = 2268 uint4
#define WS_NEED (36288 + QTOT * 16)   // 772,272 B
#define BLK 512              // 1024 blocks = 4/CU exactly (36.3KB LDS), no tail
#define PPT 2                // pixels per thread (low VGPR -> 32 waves/CU)
#define SCALE 1024.0f        // lift f16 values out of subnormal range (exact pow2)
#define INV_SCALE 0.0009765625f  // 2^-10, exact

typedef float    f2v __attribute__((ext_vector_type(2)));
typedef _Float16 h2v __attribute__((ext_vector_type(2)));
typedef _Float16 h8v __attribute__((ext_vector_type(8)));

__device__ __constant__ int c_W11[11]   = {10, 11, 13, 15, 18, 22, 26, 31, 37, 44, 52};
__device__ __constant__ int c_EOFF[12]  = {0, 100, 221, 390, 615, 939, 1423, 2099,
                                           3060, 4429, 6365, 9069};
__device__ __constant__ int c_WQ[5]     = {63, 75, 90, 108, 129};
__device__ __constant__ int c_QOFF[6]   = {0, 3969, 9594, 17694, 29358, 45999};

// Reference semantics (locked R1-R7): JAX/XLA f32:
//   hx = int32(fl32(cx*n)); bx = floorf(fl32(cx*rcp)), rcp = fl32(1/fl32(1/n));
//   NS[15] = 127.
// FINAL KERNEL = R23 (best: 40.71us). Ladder: R7 93 -> R11 47.9 -> R18 50.4
// (f16 quads verified) -> R19 42.8 -> R21 41.0 -> R23 40.7. Falsified nulls:
// VGPR cap (R24), phase interleave (R25), LDS pairing (R22), store type
// (R15: NT wins), probe re-split (R20), block specialization (R16).
// Structure: levels 0-10 from 36.3KB f16-entry LDS (4 blk/CU, 32 waves/CU =
// HW max, zero dispatch tail); levels 11-15 one 16B f16-quad load per
// pixel-level, issued before LDS compute for latency overlap; NT stores.

__device__ __forceinline__ unsigned pack_h2(float a, float b) {
    h2v h; h[0] = (_Float16)(a * SCALE); h[1] = (_Float16)(b * SCALE);
    return __builtin_bit_cast(unsigned, h);
}

// ---- phase 1: build dense scratch: f16 entries (lvls 0-10) + f16 quads (11-15) ----
__global__ __launch_bounds__(256)
void dehash_kernel(const float* __restrict__ table, unsigned* __restrict__ wsu)
{
    const int e = blockIdx.x * 256 + threadIdx.x;
    const float2* __restrict__ tab2 = reinterpret_cast<const float2*>(table);

    if (e < ETOT) {
        int l = 0;
        #pragma unroll
        for (int i = 1; i < NLDS; ++i) l += (e >= c_EOFF[i]);
        const int W   = c_W11[l];
        const int rel = e - c_EOFF[l];
        const int j   = rel / W;
        const int i2  = rel - j * W;
        const unsigned idx = ((unsigned)i2 ^ ((unsigned)j * PRIME2)) & HMASK;
        const float2 v = tab2[(size_t)l * TSIZE + idx];
        wsu[e] = pack_h2(v.x, v.y);
    } else if (e < ETOT + QTOT) {
        const int eq = e - ETOT;
        int k = 0;
        #pragma unroll
        for (int i = 1; i < 5; ++i) k += (eq >= c_QOFF[i]);
        const int W   = c_WQ[k];
        const int rel = eq - c_QOFF[k];
        const int j   = rel / W;
        const int i2  = rel - j * W;
        const float2* __restrict__ tabl = tab2 + (size_t)(11 + k) * TSIZE;
        const unsigned jp0 = (unsigned)j * PRIME2;
        const unsigned jp1 = (unsigned)(j + 1) * PRIME2;
        const float2 f00 = tabl[((unsigned)i2       ^ jp0) & HMASK];
        const float2 f10 = tabl[((unsigned)(i2 + 1) ^ jp0) & HMASK];
        const float2 f01 = tabl[((unsigned)i2       ^ jp1) & HMASK];
        const float2 f11 = tabl[((unsigned)(i2 + 1) ^ jp1) & HMASK];
        uint4 q;
        q.x = pack_h2(f00.x, f00.y);
        q.y = pack_h2(f10.x, f10.y);
        q.z = pack_h2(f01.x, f01.y);
        q.w = pack_h2(f11.x, f11.y);
        reinterpret_cast<uint4*>(wsu)[QU4_OFF + eq] = q;
    }
}

__device__ __forceinline__ float2 dec_h2(unsigned u) {
    const h2v h = __builtin_bit_cast(h2v, u);
    return make_float2((float)h[0], (float)h[1]);
}

// ---- phase 2: fused encode: 11 LDS levels + 5 quad-gather levels ----
__global__ __launch_bounds__(BLK)
void hashenc_fused(const float* __restrict__ coord,
                   const unsigned* __restrict__ wsu,
                   float* __restrict__ out)
{
    constexpr int NS[11]   = {8, 9, 11, 13, 16, 20, 24, 29, 35, 42, 50};
    constexpr int W11[11]  = {10, 11, 13, 15, 18, 22, 26, 31, 37, 44, 52};
    constexpr int EOFF[11] = {0, 100, 221, 390, 615, 939, 1423, 2099, 3060, 4429,
                              6365};
    constexpr int NSD[5]   = {61, 73, 88, 106, 127};
    constexpr int WQ[5]    = {63, 75, 90, 108, 129};
    constexpr int QOFF[5]  = {0, 3969, 9594, 17694, 29358};

    __shared__ __align__(16) unsigned smem[EPAD];   // 36,288 B -> 4 blocks/CU

    // ---- stage f16 entries from dense scratch (coalesced uint4) ----
    {
        const uint4* __restrict__ src = reinterpret_cast<const uint4*>(wsu);
        uint4* __restrict__ dst = reinterpret_cast<uint4*>(smem);
        for (int e = threadIdx.x; e < EPAD / 4; e += BLK)
            dst[e] = src[e];
    }

    const int g   = blockIdx.x * BLK + threadIdx.x;   // 0..524287
    const int P   = g << 1;                           // first of 2 pixels
    const int b   = P >> 18;                          // batch (HW = 2^18)
    const int pos = P & (HW - 1);

    const float* cbase = coord + (size_t)b * (2 * HW);
    const float2 cxp = *reinterpret_cast<const float2*>(cbase + pos);
    const float2 cyp = *reinterpret_cast<const float2*>(cbase + HW + pos);
    const float cxa[PPT] = {cxp.x, cxp.y};
    const float cya[PPT] = {cyp.x, cyp.y};

    float* outb = out + (size_t)b * (32 * HW) + pos;

    __syncthreads();

    // ---- issue all 10 direct quad loads NOW (latency hides under LDS work) ----
    uint4 q[5][PPT];
    {
        const uint4* __restrict__ quad = reinterpret_cast<const uint4*>(wsu) + QU4_OFF;
        #pragma unroll
        for (int k = 0; k < 5; ++k) {
            const float n = (float)NSD[k];
            #pragma unroll
            for (int p = 0; p < PPT; ++p) {
                const int hx = (int)(cxa[p] * n);
                const int hy = (int)(cya[p] * n);
                q[k][p] = quad[QOFF[k] + hy * WQ[k] + hx];
            }
        }
    }

    // ---- LDS levels 0..10 ----
    #pragma unroll
    for (int l = 0; l < NLDS; ++l) {
        const float n   = (float)NS[l];
        const float inv = 1.0f / n;
        const float rcp = 1.0f / inv;
        const int   W   = W11[l];
        const unsigned* __restrict__ sl = smem + EOFF[l];

        float o0[PPT], o1[PPT];
        #pragma unroll
        for (int p = 0; p < PPT; ++p) {
            const float cx = cxa[p], cy = cya[p];
            const int hx = (int)(cx * n);
            const int hy = (int)(cy * n);
            const float bx = floorf(cx * rcp);
            const float by = floorf(cy * rcp);

            const int base = hy * W + hx;
            const float2 f00 = dec_h2(sl[base]);
            const float2 f10 = dec_h2(sl[base + 1]);
            const float2 f01 = dec_h2(sl[base + W]);
            const float2 f11 = dec_h2(sl[base + W + 1]);

            const float wx_lo = ((bx + 1.0f) * inv - cx) * n;
            const float wx_hi = (cx - bx * inv) * n;
            const float wy_lo = ((by + 1.0f) * inv - cy) * n;
            const float wy_hi = (cy - by * inv) * n;

            const float r1x = f00.x * wx_lo + f10.x * wx_hi;
            const float r1y = f00.y * wx_lo + f10.y * wx_hi;
            const float r2x = f01.x * wx_lo + f11.x * wx_hi;
            const float r2y = f01.y * wx_lo + f11.y * wx_hi;
            o0[p] = (r1x * wy_lo + r2x * wy_hi) * INV_SCALE;
            o1[p] = (r1y * wy_lo + r2y * wy_hi) * INV_SCALE;
        }
        __builtin_nontemporal_store(f2v{o0[0], o0[1]},
                                    (f2v*)(outb + (size_t)(2 * l)     * HW));
        __builtin_nontemporal_store(f2v{o1[0], o1[1]},
                                    (f2v*)(outb + (size_t)(2 * l + 1) * HW));
    }

    // ---- direct levels 11..15: blend the landed quads ----
    #pragma unroll
    for (int k = 0; k < 5; ++k) {
        const int   l   = 11 + k;
        const float n   = (float)NSD[k];
        const float inv = 1.0f / n;
        const float rcp = 1.0f / inv;

        float o0[PPT], o1[PPT];
        #pragma unroll
        for (int p = 0; p < PPT; ++p) {
            const float cx = cxa[p], cy = cya[p];
            const float bx = floorf(cx * rcp);
            const float by = floorf(cy * rcp);

            const h8v h = __builtin_bit_cast(h8v, q[k][p]);

            const float wx_lo = ((bx + 1.0f) * inv - cx) * n;
            const float wx_hi = (cx - bx * inv) * n;
            const float wy_lo = ((by + 1.0f) * inv - cy) * n;
            const float wy_hi = (cy - by * inv) * n;

            const float r1x = (float)h[0] * wx_lo + (float)h[2] * wx_hi;
            const float r1y = (float)h[1] * wx_lo + (float)h[3] * wx_hi;
            const float r2x = (float)h[4] * wx_lo + (float)h[6] * wx_hi;
            const float r2y = (float)h[5] * wx_lo + (float)h[7] * wx_hi;
            o0[p] = (r1x * wy_lo + r2x * wy_hi) * INV_SCALE;
            o1[p] = (r1y * wy_lo + r2y * wy_hi) * INV_SCALE;
        }
        __builtin_nontemporal_store(f2v{o0[0], o0[1]},
                                    (f2v*)(outb + (size_t)(2 * l)     * HW));
        __builtin_nontemporal_store(f2v{o1[0], o1[1]},
                                    (f2v*)(outb + (size_t)(2 * l + 1) * HW));
    }
}

// ---- fallback (ws too small): R11 structure, proven 47.9us ----
__global__ __launch_bounds__(1024)
void hashenc_r11(const float* __restrict__ coord,
                 const float* __restrict__ table,
                 float* __restrict__ out)
{
    constexpr int NS[13]  = {8, 9, 11, 13, 16, 20, 24, 29, 35, 42, 50, 61, 73};
    constexpr int OFF[13] = {0, 100, 221, 390, 615, 939, 1423, 2099, 3060, 4429,
                             6365, 9069, 13038};
    constexpr int NSD[3]  = {88, 106, 127};

    extern __shared__ float2 smemd[];
    const float2* __restrict__ tab2 = reinterpret_cast<const float2*>(table);

    #pragma unroll
    for (int l = 0; l < 13; ++l) {
        const int W  = NS[l] + 2;
        const int SZ = W * W;
        const float2* __restrict__ tabl = tab2 + (size_t)l * TSIZE;
        for (int e = threadIdx.x; e < SZ; e += 1024) {
            const int j = e / W;
            const int i = e - j * W;
            smemd[OFF[l] + e] = tabl[((unsigned)i ^ ((unsigned)j * PRIME2)) & HMASK];
        }
    }

    const int g   = blockIdx.x * 1024 + threadIdx.x;
    const int P   = g << 1;
    const int b   = P >> 18;
    const int pos = P & (HW - 1);
    const float* cbase = coord + (size_t)b * (2 * HW);
    const float2 cxp = *reinterpret_cast<const float2*>(cbase + pos);
    const float2 cyp = *reinterpret_cast<const float2*>(cbase + HW + pos);
    const float cxa[2] = {cxp.x, cxp.y};
    const float cya[2] = {cyp.x, cyp.y};
    float* outb = out + (size_t)b * (32 * HW) + pos;

    __syncthreads();

    float2 gd[3][8];
    #pragma unroll
    for (int k = 0; k < 3; ++k) {
        const float n = (float)NSD[k];
        const float2* __restrict__ tabl = tab2 + (size_t)(13 + k) * TSIZE;
        #pragma unroll
        for (int p = 0; p < 2; ++p) {
            const int hx = (int)(cxa[p] * n);
            const int hy = (int)(cya[p] * n);
            const unsigned hyp0 = (unsigned)hy * PRIME2;
            const unsigned hyp1 = (unsigned)(hy + 1) * PRIME2;
            gd[k][p * 4 + 0] = tabl[((unsigned)hx       ^ hyp0) & HMASK];
            gd[k][p * 4 + 1] = tabl[((unsigned)(hx + 1) ^ hyp0) & HMASK];
            gd[k][p * 4 + 2] = tabl[((unsigned)hx       ^ hyp1) & HMASK];
            gd[k][p * 4 + 3] = tabl[((unsigned)(hx + 1) ^ hyp1) & HMASK];
        }
    }

    #pragma unroll
    for (int l = 0; l < 13; ++l) {
        const float n   = (float)NS[l];
        const float inv = 1.0f / n;
        const float rcp = 1.0f / inv;
        const int   W   = NS[l] + 2;
        const float2* __restrict__ sl = smemd + OFF[l];
        float o0[2], o1[2];
        #pragma unroll
        for (int p = 0; p < 2; ++p) {
            const float cx = cxa[p], cy = cya[p];
            const int hx = (int)(cx * n);
            const int hy = (int)(cy * n);
            const float bx = floorf(cx * rcp);
            const float by = floorf(cy * rcp);
            const int base = hy * W + hx;
            const float2 f00 = sl[base], f10 = sl[base + 1];
            const float2 f01 = sl[base + W], f11 = sl[base + W + 1];
            const float wx_lo = ((bx + 1.0f) * inv - cx) * n;
            const float wx_hi = (cx - bx * inv) * n;
            const float wy_lo = ((by + 1.0f) * inv - cy) * n;
            const float wy_hi = (cy - by * inv) * n;
            const float r1x = f00.x * wx_lo + f10.x * wx_hi;
            const float r1y = f00.y * wx_lo + f10.y * wx_hi;
            const float r2x = f01.x * wx_lo + f11.x * wx_hi;
            const float r2y = f01.y * wx_lo + f11.y * wx_hi;
            o0[p] = r1x * wy_lo + r2x * wy_hi;
            o1[p] = r1y * wy_lo + r2y * wy_hi;
        }
        *reinterpret_cast<float2*>(outb + (size_t)(2 * l)     * HW) = make_float2(o0[0], o0[1]);
        *reinterpret_cast<float2*>(outb + (size_t)(2 * l + 1) * HW) = make_float2(o1[0], o1[1]);
    }

    #pragma unroll
    for (int k = 0; k < 3; ++k) {
        const int   l   = 13 + k;
        const float n   = (float)NSD[k];
        const float inv = 1.0f / n;
        const float rcp = 1.0f / inv;
        float o0[2], o1[2];
        #pragma unroll
        for (int p = 0; p < 2; ++p) {
            const float cx = cxa[p], cy = cya[p];
            const float bx = floorf(cx * rcp);
            const float by = floorf(cy * rcp);
            const float2 f00 = gd[k][p * 4 + 0], f10 = gd[k][p * 4 + 1];
            const float2 f01 = gd[k][p * 4 + 2], f11 = gd[k][p * 4 + 3];
            const float wx_lo = ((bx + 1.0f) * inv - cx) * n;
            const float wx_hi = (cx - bx * inv) * n;
            const float wy_lo = ((by + 1.0f) * inv - cy) * n;
            const float wy_hi = (cy - by * inv) * n;
            const float r1x = f00.x * wx_lo + f10.x * wx_hi;
            const float r1y = f00.y * wx_lo + f10.y * wx_hi;
            const float r2x = f01.x * wx_lo + f11.x * wx_hi;
            const float r2y = f01.y * wx_lo + f11.y * wx_hi;
            o0[p] = r1x * wy_lo + r2x * wy_hi;
            o1[p] = r1y * wy_lo + r2y * wy_hi;
        }
        *reinterpret_cast<float2*>(outb + (size_t)(2 * l)     * HW) = make_float2(o0[0], o0[1]);
        *reinterpret_cast<float2*>(outb + (size_t)(2 * l + 1) * HW) = make_float2(o1[0], o1[1]);
    }
}

extern "C" void kernel_launch(void* const* d_in, const int* in_sizes, int n_in,
                              void* d_out, int out_size, void* d_ws, size_t ws_size,
                              hipStream_t stream) {
    const float* coord = (const float*)d_in[0];
    const float* table = (const float*)d_in[1];
    if (n_in >= 2 && in_sizes[0] > in_sizes[1]) {   // size-based disambiguation
        coord = (const float*)d_in[1];
        table = (const float*)d_in[0];
    }
    float* out = (float*)d_out;

    if (ws_size >= (size_t)WS_NEED && d_ws != nullptr) {
        unsigned* wsu = (unsigned*)d_ws;
        // phase 1: 9069 entries + 45999 quad cells = 55068 -> 216 blocks
        dehash_kernel<<<(ETOT + QTOT + 255) / 256, 256, 0, stream>>>(table, wsu);
        // phase 2: 1M px / (512 thr * 2 px) = 1024 blocks = 4/CU exactly (no tail)
        hashenc_fused<<<1024, BLK, 0, stream>>>(coord, wsu, out);
    } else {
        const int lds_bytes = 18663 * (int)sizeof(float2);
        (void)hipFuncSetAttribute((const void*)hashenc_r11,
                                  hipFuncAttributeMaxDynamicSharedMemorySize,
                                  lds_bytes);
        hashenc_r11<<<512, 1024, lds_bytes, stream>>>(coord, table, out);
    }
}